// Round 1
// 658.170 us; speedup vs baseline: 1.1787x; 1.1787x over previous
//
#include <hip/hip_runtime.h>
#include <hip/hip_bf16.h>

#define N_ROWS 2048
#define D_DIM 1024
#define V_DIM 32000
#define K_NN 32
#define KDIM 2048  // 2*D

typedef short short8 __attribute__((ext_vector_type(8)));
typedef float f32x4 __attribute__((ext_vector_type(4)));
typedef unsigned short us4 __attribute__((ext_vector_type(4)));

__device__ __forceinline__ unsigned short f2bf(float x) {
  __hip_bfloat16 h = __float2bfloat16(x);
  return *reinterpret_cast<unsigned short*>(&h);
}

// ---------------------------------------------------------------- K0: prep
// convert mw_w1 (1024x2048 fp32) -> bf16 in ws; zero mix_acc[N]
__global__ __launch_bounds__(256) void k0_prep(const float* __restrict__ w1,
                                               __hip_bfloat16* __restrict__ w1bf,
                                               float* __restrict__ mix_acc) {
  int idx = blockIdx.x * 256 + threadIdx.x;
  int e4 = idx * 4;
  if (e4 < D_DIM * KDIM) {
    float4 v = *(const float4*)(w1 + e4);
    us4 u = {f2bf(v.x), f2bf(v.y), f2bf(v.z), f2bf(v.w)};
    *(us4*)((unsigned short*)w1bf + e4) = u;
  }
  if (idx < N_ROWS) mix_acc[idx] = 0.f;
}

// ---------------------------------------------------------------- K1: feat
// per row n: ctx = mean_k searched; featbf = [h, ctx] bf16; bandwidth dot;
// knn softmax weights.
__global__ __launch_bounds__(256) void k1_feat(const float* __restrict__ hidden,
                                               const float* __restrict__ searched,
                                               const float* __restrict__ distances,
                                               const float* __restrict__ bw_w,
                                               const float* __restrict__ bw_b,
                                               __hip_bfloat16* __restrict__ featbf,
                                               float* __restrict__ knn_w) {
  const int n = blockIdx.x;
  const int t = threadIdx.x;  // 256 threads, each owns float4 chunk t (D=1024)
  const float4* sh4 = (const float4*)(searched + (size_t)n * K_NN * D_DIM);
  float4 acc = {0.f, 0.f, 0.f, 0.f};
#pragma unroll 4
  for (int k = 0; k < K_NN; ++k) {
    float4 v = sh4[k * (D_DIM / 4) + t];
    acc.x += v.x; acc.y += v.y; acc.z += v.z; acc.w += v.w;
  }
  const float s = 1.0f / 32.0f;
  float4 ctx = {acc.x * s, acc.y * s, acc.z * s, acc.w * s};
  float4 h4 = ((const float4*)(hidden + (size_t)n * D_DIM))[t];

  us4 uh = {f2bf(h4.x), f2bf(h4.y), f2bf(h4.z), f2bf(h4.w)};
  us4 uc = {f2bf(ctx.x), f2bf(ctx.y), f2bf(ctx.z), f2bf(ctx.w)};
  unsigned short* fb = (unsigned short*)featbf + (size_t)n * KDIM;
  *(us4*)(fb + t * 4) = uh;
  *(us4*)(fb + D_DIM + t * 4) = uc;

  const float4 b0 = ((const float4*)bw_w)[t];
  const float4 b1v = ((const float4*)bw_w)[D_DIM / 4 + t];
  float part = h4.x * b0.x + h4.y * b0.y + h4.z * b0.z + h4.w * b0.w +
               ctx.x * b1v.x + ctx.y * b1v.y + ctx.z * b1v.z + ctx.w * b1v.w;

  __shared__ float red[4];
  __shared__ float sBW;
#pragma unroll
  for (int mask = 32; mask >= 1; mask >>= 1) part += __shfl_xor(part, mask, 64);
  if ((t & 63) == 0) red[t >> 6] = part;
  __syncthreads();
  if (t == 0) sBW = __expf(red[0] + red[1] + red[2] + red[3] + bw_b[0]);
  __syncthreads();

  if (t < K_NN) {
    float x = -distances[n * K_NN + t] / sBW;
    float m = x;
#pragma unroll
    for (int mask = 16; mask >= 1; mask >>= 1) m = fmaxf(m, __shfl_xor(m, mask, 64));
    float e = __expf(x - m);
    float ssum = e;
#pragma unroll
    for (int mask = 16; mask >= 1; mask >>= 1) ssum += __shfl_xor(ssum, mask, 64);
    knn_w[n * K_NN + t] = e / ssum;
  }
}

// ---------------------------------------------------------------- K2: MLP GEMM
// mhid[n,d] = feat[n,:] . w1[d,:]  (bf16 MFMA), fused relu(.+b1)*w2[d],
// row-reduced, atomicAdd into mix_acc[n].
// BM=BN=BK=64, 256 thr (4 waves), wave computes 32x32 (2x2 of 16x16x32 tiles).
__global__ __launch_bounds__(256) void k2_gemm(const __hip_bfloat16* __restrict__ A,
                                               const __hip_bfloat16* __restrict__ B,
                                               const float* __restrict__ b1,
                                               const float* __restrict__ w2,
                                               float* __restrict__ mix_acc) {
  __shared__ __align__(16) __hip_bfloat16 As[64 * 64];
  __shared__ __align__(16) __hip_bfloat16 Bs[64 * 64];
  const int tid = threadIdx.x;
  const int lane = tid & 63;
  const int wv = tid >> 6;
  const int bm0 = blockIdx.y * 64;
  const int bn0 = blockIdx.x * 64;
  const int wm = (wv & 1) * 32;
  const int wn = (wv >> 1) * 32;

  f32x4 acc[2][2] = {};

  // staging: lane L covers (row = r0 + L>>3, chunk-slot L&7); global chunk is
  // XOR-swizzled by row so fragment ds_read_b128 is ~conflict-free.
  const int srow = lane >> 3;
  const int cs = lane & 7;
  const int cg = cs ^ srow;  // srow in 0..7

  for (int kt = 0; kt < KDIM / 64; ++kt) {
#pragma unroll
    for (int it = 0; it < 2; ++it) {
      const int r0 = (wv * 2 + it) * 8;
      const int row = r0 + srow;
      const __hip_bfloat16* ga = A + ((size_t)(bm0 + row) * KDIM + kt * 64 + cg * 8);
      const __hip_bfloat16* gb = B + ((size_t)(bn0 + row) * KDIM + kt * 64 + cg * 8);
      __builtin_amdgcn_global_load_lds((__attribute__((address_space(1))) void*)ga,
                                       (__attribute__((address_space(3))) void*)(&As[r0 * 64]),
                                       16, 0, 0);
      __builtin_amdgcn_global_load_lds((__attribute__((address_space(1))) void*)gb,
                                       (__attribute__((address_space(3))) void*)(&Bs[r0 * 64]),
                                       16, 0, 0);
    }
    __syncthreads();
#pragma unroll
    for (int ks = 0; ks < 2; ++ks) {
      short8 af[2], bfr[2];
#pragma unroll
      for (int mt = 0; mt < 2; ++mt) {
        int row = wm + mt * 16 + (lane & 15);
        int c = (ks * 4 + (lane >> 4)) ^ (row & 7);
        af[mt] = *(const short8*)&As[row * 64 + c * 8];
      }
#pragma unroll
      for (int nt = 0; nt < 2; ++nt) {
        int row = wn + nt * 16 + (lane & 15);
        int c = (ks * 4 + (lane >> 4)) ^ (row & 7);
        bfr[nt] = *(const short8*)&Bs[row * 64 + c * 8];
      }
#pragma unroll
      for (int mt = 0; mt < 2; ++mt)
#pragma unroll
        for (int nt = 0; nt < 2; ++nt)
          acc[mt][nt] = __builtin_amdgcn_mfma_f32_16x16x32_bf16(af[mt], bfr[nt], acc[mt][nt], 0, 0, 0);
    }
    __syncthreads();
  }

  // epilogue: C/D layout col=lane&15 (-> d), row=(lane>>4)*4+reg (-> n)
  float contrib[2][4];
#pragma unroll
  for (int mt = 0; mt < 2; ++mt)
#pragma unroll
    for (int r = 0; r < 4; ++r) contrib[mt][r] = 0.f;
#pragma unroll
  for (int nt = 0; nt < 2; ++nt) {
    int d = bn0 + wn + nt * 16 + (lane & 15);
    float w2d = w2[d];
    float b1d = b1[d];
#pragma unroll
    for (int mt = 0; mt < 2; ++mt)
#pragma unroll
      for (int r = 0; r < 4; ++r) {
        float h = acc[mt][nt][r] + b1d;
        h = h > 0.f ? h : 0.f;
        contrib[mt][r] = fmaf(h, w2d, contrib[mt][r]);
      }
  }
#pragma unroll
  for (int mask = 1; mask < 16; mask <<= 1)
#pragma unroll
    for (int mt = 0; mt < 2; ++mt)
#pragma unroll
      for (int r = 0; r < 4; ++r)
        contrib[mt][r] += __shfl_xor(contrib[mt][r], mask, 64);
  if ((lane & 15) == 0) {
    int rbase = bm0 + wm + (lane >> 4) * 4;
#pragma unroll
    for (int mt = 0; mt < 2; ++mt)
#pragma unroll
      for (int r = 0; r < 4; ++r)
        atomicAdd(&mix_acc[rbase + mt * 16 + r], contrib[mt][r]);
  }
}

// ---------------------------------------------------------------- K3: output
// per row: softmax over V (regs+LDS), mix, log, scatter fixup for top-k tokens.
// NOTE: the 3-pass logits cache r[16] MUST be statically indexed (fixed j=0..15
// unroll, runtime guard only on the last iter) or it spills to scratch
// (rule #20): previous version had VGPR=52 + ~394 MB of excess HBM traffic.
__global__ __launch_bounds__(512, 4) void k3_out(const float* __restrict__ logits,
                                                 const int* __restrict__ tok,
                                                 const float* __restrict__ knn_w,
                                                 const float* __restrict__ mix_acc,
                                                 const float* __restrict__ mw_b2,
                                                 float* __restrict__ out) {
  const int n = blockIdx.x;
  const int t = threadIdx.x;  // 512 threads
  __shared__ __align__(8) unsigned short eL[V_DIM];  // exp(x-M) as bf16, for fixup gather
  __shared__ float red[8];
  __shared__ float sM, sS;

  const float4* lg4 = (const float4*)(logits + (size_t)n * V_DIM);
  // V_DIM/4 = 8000 = 15*512 + 320: iterations j<15 are unconditionally in
  // range for every t (max i = 511 + 14*512 = 7679); only j==15 needs a guard.
  float4 r[16];
  float vmax = -3.0e38f;
#pragma unroll
  for (int j = 0; j < 16; ++j) {
    int i = t + j * 512;
    if (j < 15 || i < V_DIM / 4) {
      float4 v = lg4[i];
      r[j] = v;
      vmax = fmaxf(vmax, fmaxf(fmaxf(v.x, v.y), fmaxf(v.z, v.w)));
    }
  }
#pragma unroll
  for (int mask = 32; mask >= 1; mask >>= 1) vmax = fmaxf(vmax, __shfl_xor(vmax, mask, 64));
  if ((t & 63) == 0) red[t >> 6] = vmax;
  __syncthreads();
  if (t == 0) {
    float m = red[0];
    for (int i = 1; i < 8; ++i) m = fmaxf(m, red[i]);
    sM = m;
  }
  __syncthreads();
  const float M = sM;

  float lsum = 0.f;
#pragma unroll
  for (int j = 0; j < 16; ++j) {
    int i = t + j * 512;
    if (j < 15 || i < V_DIM / 4) {
      float4 v = r[j];
      float e0 = __expf(v.x - M), e1 = __expf(v.y - M);
      float e2 = __expf(v.z - M), e3 = __expf(v.w - M);
      lsum += (e0 + e1) + (e2 + e3);
      us4 u = {f2bf(e0), f2bf(e1), f2bf(e2), f2bf(e3)};
      *(us4*)&eL[i * 4] = u;
    }
  }
#pragma unroll
  for (int mask = 32; mask >= 1; mask >>= 1) lsum += __shfl_xor(lsum, mask, 64);
  if ((t & 63) == 0) red[t >> 6] = lsum;
  __syncthreads();
  if (t == 0) {
    float ss = 0.f;
    for (int i = 0; i < 8; ++i) ss += red[i];
    sS = ss;
  }
  __syncthreads();

  const float inv = 1.0f / sS;
  const float mix = 1.0f / (1.0f + __expf(-(mix_acc[n] + mw_b2[0])));
  const float a = (1.0f - mix) * inv;

  float4* out4 = (float4*)(out + (size_t)n * V_DIM);
#pragma unroll
  for (int j = 0; j < 16; ++j) {
    int i = t + j * 512;
    if (j < 15 || i < V_DIM / 4) {
      float4 v = r[j];
      float4 o;
      o.x = __logf(fmaf(__expf(v.x - M), a, 1e-10f));
      o.y = __logf(fmaf(__expf(v.y - M), a, 1e-10f));
      o.z = __logf(fmaf(__expf(v.z - M), a, 1e-10f));
      o.w = __logf(fmaf(__expf(v.w - M), a, 1e-10f));
      out4[i] = o;
    }
  }
  __syncthreads();  // drains vmcnt: base writes complete before fixup overwrites

  if (t < K_NN) {
    int myidx = tok[n * K_NN + t];
    float w = knn_w[n * K_NN + t];
    float tot = 0.f;
    int first = t;
    for (int j = 0; j < K_NN; ++j) {
      int ij = __shfl(myidx, j, 64);
      float wj = __shfl(w, j, 64);
      if (ij == myidx) {
        tot += wj;
        if (j < first) first = j;
      }
    }
    if (first == t) {  // first occurrence writes merged weight (matches .at[].add)
      __hip_bfloat16 hb = *reinterpret_cast<__hip_bfloat16*>(&eL[myidx]);
      float e = __bfloat162float(hb);
      out[(size_t)n * V_DIM + myidx] = __logf((1.0f - mix) * e * inv + mix * tot + 1e-10f);
    }
  }
}

// ---------------------------------------------------------------- launch
extern "C" void kernel_launch(void* const* d_in, const int* in_sizes, int n_in,
                              void* d_out, int out_size, void* d_ws, size_t ws_size,
                              hipStream_t stream) {
  const float* hidden    = (const float*)d_in[0];
  const float* logits    = (const float*)d_in[1];
  const float* distances = (const float*)d_in[2];
  const int*   tok       = (const int*)d_in[3];
  const float* searched  = (const float*)d_in[4];
  const float* bw_w      = (const float*)d_in[5];
  const float* bw_b      = (const float*)d_in[6];
  const float* mw_w1     = (const float*)d_in[7];
  const float* mw_b1     = (const float*)d_in[8];
  const float* mw_w2     = (const float*)d_in[9];
  const float* mw_b2     = (const float*)d_in[10];
  float* out = (float*)d_out;

  char* ws = (char*)d_ws;
  __hip_bfloat16* w1bf   = (__hip_bfloat16*)(ws + 0);          // 4,194,304 B
  __hip_bfloat16* featbf = (__hip_bfloat16*)(ws + 4194304);    // 8,388,608 B
  float*          knn_w  = (float*)(ws + 12582912);            //   262,144 B
  float*          mix_acc= (float*)(ws + 12845056);            //     8,192 B

  hipLaunchKernelGGL(k0_prep, dim3(2048), dim3(256), 0, stream, mw_w1, w1bf, mix_acc);
  hipLaunchKernelGGL(k1_feat, dim3(N_ROWS), dim3(256), 0, stream,
                     hidden, searched, distances, bw_w, bw_b, featbf, knn_w);
  hipLaunchKernelGGL(k2_gemm, dim3(D_DIM / 64, N_ROWS / 64), dim3(256), 0, stream,
                     featbf, w1bf, mw_b1, mw_w2, mix_acc);
  hipLaunchKernelGGL(k3_out, dim3(N_ROWS), dim3(512), 0, stream,
                     logits, tok, knn_w, mix_acc, mw_b2, out);
}